// Round 3
// baseline (610.793 us; speedup 1.0000x reference)
//
#include <hip/hip_runtime.h>
#include <stdint.h>

// ---------------------------------------------------------------------------
// QuantizedLinear: out[M,N] = x[M,K] @ dequant(qweight)[N,K]^T
//   M = B*S = 8192, K = IN = 4096, N = OUT = 4096
//   4-bit weights, group=128, w = scale * (q - zero)
// Strategy: dequant W -> bf16 (N,K), cast x -> bf16 (M,K), then m97-structure
// bf16 MFMA GEMM-BT (128x128 tile, BK=32, global_load_lds width 16).
// ---------------------------------------------------------------------------

typedef short bf16x8 __attribute__((ext_vector_type(8)));  // 8 bf16 bit-patterns
typedef float f32x4 __attribute__((ext_vector_type(4)));
typedef unsigned short u16x4 __attribute__((ext_vector_type(4)));
typedef unsigned short u16x8 __attribute__((ext_vector_type(8)));

#define BM 128
#define BN 128
#define BK 32

// round-to-nearest-even f32 -> bf16 bits
__device__ __forceinline__ unsigned short f2bf(float f) {
  unsigned int u = __builtin_bit_cast(unsigned int, f);
  u += 0x7FFFu + ((u >> 16) & 1u);
  return (unsigned short)(u >> 16);
}

// async global->LDS, 16B per lane. LDS dest: wave-uniform base (+lane*16 by HW).
__device__ __forceinline__ void gload_lds16(const void* g, void* l) {
  const __attribute__((address_space(1))) unsigned int* gp =
      (const __attribute__((address_space(1))) unsigned int*)(uintptr_t)g;
  __attribute__((address_space(3))) unsigned int* lp =
      (__attribute__((address_space(3))) unsigned int*)(unsigned int)(uintptr_t)l;
  __builtin_amdgcn_global_load_lds(gp, lp, 16, 0, 0);
}

// ---------------------------------------------------------------------------
// x: fp32 -> bf16 bits (4 elems/thread)
// ---------------------------------------------------------------------------
__global__ void xcast_kernel(const float* __restrict__ x,
                             unsigned short* __restrict__ y, int n4) {
  int tid = blockIdx.x * blockDim.x + threadIdx.x;
  if (tid >= n4) return;
  const float4 v = reinterpret_cast<const float4*>(x)[tid];
  u16x4 o;
  o[0] = f2bf(v.x);
  o[1] = f2bf(v.y);
  o[2] = f2bf(v.z);
  o[3] = f2bf(v.w);
  reinterpret_cast<u16x4*>(y)[tid] = o;
}

// ---------------------------------------------------------------------------
// dequant: qweight (O=4096, P=2048) int32 (one byte-value each: 2 nibbles,
//          low first) -> w bf16 (O, I=4096) row-major. group = 128 elems
//          = 64 ints. One thread: 4 ints (int4) -> 8 bf16 (16B store).
//          Aligned-4 ints never cross a group boundary -> one scale/zero load.
// ---------------------------------------------------------------------------
__global__ void dequant_kernel(const int* __restrict__ qw,
                               const float* __restrict__ scale,
                               const float* __restrict__ zero,
                               unsigned short* __restrict__ w) {
  int tid = blockIdx.x * blockDim.x + threadIdx.x;
  const int4 q = reinterpret_cast<const int4*>(qw)[tid];
  int pi0 = tid << 2;       // packed-int index
  int o = pi0 >> 11;        // P = 2048 ints per O-row
  int p = pi0 & 2047;
  int g = p >> 6;           // 64 ints per group
  float s = scale[(o << 5) + g];  // 32 groups per row
  float z = zero[(o << 5) + g];
  int qs[4] = {q.x, q.y, q.z, q.w};
  u16x8 ov;
#pragma unroll
  for (int j = 0; j < 4; ++j) {
    ov[2 * j]     = f2bf(((float)(qs[j] & 0xF) - z) * s);
    ov[2 * j + 1] = f2bf(((float)((qs[j] >> 4) & 0xF) - z) * s);
  }
  reinterpret_cast<u16x8*>(w)[tid] = ov;
}

// ---------------------------------------------------------------------------
// GEMM-BT: C[M,N] = A[M,K] * B[N,K]^T, bf16 inputs, fp32 out.
// m97 structure: 128x128 tile, BK=32, 256 threads (4 waves 2x2, 64x64/wave),
// acc[4][4] f32x4, single-buffer LDS, 2 barriers/K-step,
// global_load_lds dwordx4 staging, bijective XCD swizzle.
// ---------------------------------------------------------------------------
__global__ void __launch_bounds__(256) gemm_bt_bf16(
    const unsigned short* __restrict__ A,  // [M][K] bf16 bits
    const unsigned short* __restrict__ B,  // [N][K] bf16 bits
    float* __restrict__ C, int M, int N, int K) {
  __shared__ unsigned short sA[BM * BK];  // 8 KB, row-major [128][32]
  __shared__ unsigned short sB[BN * BK];  // 8 KB

  const int t = threadIdx.x;
  const int wave = t >> 6;
  const int lane = t & 63;

  // XCD-aware bijective swizzle (grid size 2048, a multiple of 8)
  const int nbx = N / BN;
  const int nwg = gridDim.x;
  const int bsw = (blockIdx.x & 7) * (nwg >> 3) + (blockIdx.x >> 3);
  const int br = bsw / nbx;
  const int bc = bsw % nbx;

  const int wr = wave >> 1;
  const int wc = wave & 1;

  const size_t Kb = (size_t)K * 2;  // bytes per row

  // Staging: tile is 8192 B = 2 insts x 4 waves x 64 lanes x 16 B.
  // Linear byte off within tile == row*64 + colb (row-major [128][32] bf16).
  const int lin0 = wave * 1024 + lane * 16;
  const int lin1 = lin0 + 4096;
  const int r0 = lin0 >> 6, c0 = lin0 & 63;
  const int r1 = lin1 >> 6, c1 = lin1 & 63;

  const char* aSrc0 = (const char*)A + (size_t)(br * BM + r0) * Kb + c0;
  const char* aSrc1 = (const char*)A + (size_t)(br * BM + r1) * Kb + c1;
  const char* bSrc0 = (const char*)B + (size_t)(bc * BN + r0) * Kb + c0;
  const char* bSrc1 = (const char*)B + (size_t)(bc * BN + r1) * Kb + c1;

  char* aDst0 = (char*)sA + wave * 1024;         // wave-uniform segment bases
  char* aDst1 = (char*)sA + 4096 + wave * 1024;
  char* bDst0 = (char*)sB + wave * 1024;
  char* bDst1 = (char*)sB + 4096 + wave * 1024;

  f32x4 acc[4][4];
#pragma unroll
  for (int m = 0; m < 4; ++m)
#pragma unroll
    for (int n = 0; n < 4; ++n) acc[m][n] = (f32x4){0.f, 0.f, 0.f, 0.f};

  // fragment read offsets (elements): lane&15 -> row, lane>>4 -> k-chunk of 8
  const int aoff = (wr * 64 + (lane & 15)) * BK + (lane >> 4) * 8;
  const int boff = (wc * 64 + (lane & 15)) * BK + (lane >> 4) * 8;

  const int nk = K / BK;

  gload_lds16(aSrc0, aDst0);
  gload_lds16(aSrc1, aDst1);
  gload_lds16(bSrc0, bDst0);
  gload_lds16(bSrc1, bDst1);
  aSrc0 += 2 * BK; aSrc1 += 2 * BK; bSrc0 += 2 * BK; bSrc1 += 2 * BK;

  for (int kt = 0; kt < nk; ++kt) {
    __syncthreads();  // drains vmcnt(0): staged tile visible
    bf16x8 af[4], bfr[4];
#pragma unroll
    for (int m = 0; m < 4; ++m)
      af[m] = *reinterpret_cast<const bf16x8*>(sA + aoff + m * 16 * BK);
#pragma unroll
    for (int n = 0; n < 4; ++n)
      bfr[n] = *reinterpret_cast<const bf16x8*>(sB + boff + n * 16 * BK);
#pragma unroll
    for (int m = 0; m < 4; ++m)
#pragma unroll
      for (int n = 0; n < 4; ++n)
        acc[m][n] =
            __builtin_amdgcn_mfma_f32_16x16x32_bf16(af[m], bfr[n], acc[m][n], 0, 0, 0);
    if (kt + 1 < nk) {
      __syncthreads();  // all reads done before overwrite
      gload_lds16(aSrc0, aDst0);
      gload_lds16(aSrc1, aDst1);
      gload_lds16(bSrc0, bDst0);
      gload_lds16(bSrc1, bDst1);
      aSrc0 += 2 * BK; aSrc1 += 2 * BK; bSrc0 += 2 * BK; bSrc1 += 2 * BK;
    }
  }

  // C/D layout: col = lane&15, row = (lane>>4)*4 + reg  [m89/m91 verified]
  const int row0 = br * BM + wr * 64 + (lane >> 4) * 4;
  const int col0 = bc * BN + wc * 64 + (lane & 15);
#pragma unroll
  for (int m = 0; m < 4; ++m)
#pragma unroll
    for (int r = 0; r < 4; ++r) {
      float* crow = C + (size_t)(row0 + m * 16 + r) * N + col0;
#pragma unroll
      for (int n = 0; n < 4; ++n) crow[n * 16] = acc[m][n][r];
    }
}

// ---------------------------------------------------------------------------
extern "C" void kernel_launch(void* const* d_in, const int* in_sizes, int n_in,
                              void* d_out, int out_size, void* d_ws, size_t ws_size,
                              hipStream_t stream) {
  const float* x = (const float*)d_in[0];
  const int* qw = (const int*)d_in[1];
  const float* scale = (const float*)d_in[2];
  const float* zero = (const float*)d_in[3];
  float* out = (float*)d_out;

  const int K = 4096;             // IN
  const int N = 4096;             // OUT
  const int M = in_sizes[0] / K;  // B*S = 8192

  unsigned short* xb = (unsigned short*)d_ws;        // M*K bf16 = 64 MB
  unsigned short* wb = xb + (size_t)M * K;           // N*K bf16 = 32 MB

  {
    int n4 = (M * K) / 4;
    xcast_kernel<<<(n4 + 255) / 256, 256, 0, stream>>>(x, xb, n4);
  }
  {
    int nthr = (N * (K / 2)) / 4;  // 4 packed ints per thread
    dequant_kernel<<<nthr / 256, 256, 0, stream>>>(qw, scale, zero, wb);
  }
  {
    dim3 grid((M / BM) * (N / BN));  // 64*32 = 2048, %8 == 0 for swizzle
    gemm_bt_bf16<<<grid, 256, 0, stream>>>(xb, wb, out, M, N, K);
  }
}

// Round 5
// 484.283 us; speedup vs baseline: 1.2612x; 1.2612x over previous
//
#include <hip/hip_runtime.h>
#include <stdint.h>

// ---------------------------------------------------------------------------
// QuantizedLinear: out[M,N] = x[M,K] @ dequant(qweight)[N,K]^T
//   M = 8192, K = 4096, N = 4096; 4-bit weights, group=128, w = s*(q - z)
// GEMM: 256x256 8-phase schedule (T3+T4+T2+T5+T1):
//   BK=64, 8 waves (2Mx4N), 128KB LDS double-buffer, counted vmcnt(6),
//   XOR-swizzled LDS reads with pre-swizzled global_load_lds sources.
// ---------------------------------------------------------------------------

typedef short bf16x8 __attribute__((ext_vector_type(8)));
typedef float f32x4 __attribute__((ext_vector_type(4)));
typedef unsigned short u16x4 __attribute__((ext_vector_type(4)));
typedef unsigned short u16x8 __attribute__((ext_vector_type(8)));

#define BM 256
#define BN 256
#define BK 64
#define NT 64  // K / BK

#define BAR() asm volatile("s_barrier" ::: "memory")
#define VMCNT6() asm volatile("s_waitcnt vmcnt(6)" ::: "memory")
#define VMCNT0() asm volatile("s_waitcnt vmcnt(0)" ::: "memory")

// round-to-nearest-even f32 -> bf16 bits
__device__ __forceinline__ unsigned short f2bf(float f) {
  unsigned int u = __builtin_bit_cast(unsigned int, f);
  u += 0x7FFFu + ((u >> 16) & 1u);
  return (unsigned short)(u >> 16);
}

// async global->LDS, 16B/lane. LDS dest is wave-uniform base (+lane*16 by HW).
__device__ __forceinline__ void gload_lds16(const void* g, void* l) {
  const __attribute__((address_space(1))) unsigned int* gp =
      (const __attribute__((address_space(1))) unsigned int*)(uintptr_t)g;
  __attribute__((address_space(3))) unsigned int* lp =
      (__attribute__((address_space(3))) unsigned int*)(unsigned int)(uintptr_t)l;
  __builtin_amdgcn_global_load_lds(gp, lp, 16, 0, 0);
}

// ---------------------------------------------------------------------------
__global__ void xcast_kernel(const float* __restrict__ x,
                             unsigned short* __restrict__ y, int n4) {
  int tid = blockIdx.x * blockDim.x + threadIdx.x;
  if (tid >= n4) return;
  const float4 v = reinterpret_cast<const float4*>(x)[tid];
  u16x4 o;
  o[0] = f2bf(v.x);
  o[1] = f2bf(v.y);
  o[2] = f2bf(v.z);
  o[3] = f2bf(v.w);
  reinterpret_cast<u16x4*>(y)[tid] = o;
}

// ---------------------------------------------------------------------------
__global__ void dequant_kernel(const int* __restrict__ qw,
                               const float* __restrict__ scale,
                               const float* __restrict__ zero,
                               unsigned short* __restrict__ w) {
  int tid = blockIdx.x * blockDim.x + threadIdx.x;
  const int4 q = reinterpret_cast<const int4*>(qw)[tid];
  int pi0 = tid << 2;
  int o = pi0 >> 11;
  int p = pi0 & 2047;
  int g = p >> 6;
  float s = scale[(o << 5) + g];
  float z = zero[(o << 5) + g];
  int qs[4] = {q.x, q.y, q.z, q.w};
  u16x8 ov;
#pragma unroll
  for (int j = 0; j < 4; ++j) {
    ov[2 * j]     = f2bf(((float)(qs[j] & 0xF) - z) * s);
    ov[2 * j + 1] = f2bf(((float)((qs[j] >> 4) & 0xF) - z) * s);
  }
  reinterpret_cast<u16x8*>(w)[tid] = ov;
}

// ---------------------------------------------------------------------------
// 256x256 8-phase GEMM-BT. LDS map (per buffer c at c*65536):
//   A: [half h][128 rows][64 cols bf16] at +h*16384 (row stride 128B)
//   B: same at +32768.
// Read swizzle: colbyte ^= (row&7)<<4 (2-way conflict, free). Staged with
// linear LDS dest + inverse-swizzled global source (involution).
// Staging: per K-tile q0 stages B-half1(kt+1)->other buf (2 issues);
// q3 stages A0,A1,B0(kt+2)->current buf (6 issues); vmcnt(6) at q3 retires
// exactly kt+1's 8 loads, keeping 3 half-tiles in flight.
// ---------------------------------------------------------------------------
__global__ void __launch_bounds__(512, 2) gemm_bt_bf16(
    const unsigned short* __restrict__ A,  // [M][K] bf16 bits
    const unsigned short* __restrict__ Bm, // [N][K] bf16 bits
    float* __restrict__ C, int M, int N, int K) {
  __shared__ char lds[131072];

  const int t = threadIdx.x;
  const int w = t >> 6;   // wave 0..7
  const int l = t & 63;

  const int nbx = N / BN;      // 16
  const int nwg = gridDim.x;   // 512 (multiple of 8)
  const int bsw = (blockIdx.x & 7) * (nwg >> 3) + (blockIdx.x >> 3);
  const int bm = bsw / nbx;
  const int bn = bsw % nbx;

  const int wr = w >> 2;  // 0..1 (M)
  const int wc = w & 3;   // 0..3 (N)

  const size_t Kb = (size_t)K * 2;

  // --- staging per-thread source pieces (pre-swizzled global source) ---
  const int tr = w * 8 + (l >> 3);                 // row 0..63 within an issue
  const int tc = (((l & 7) ^ (l >> 3)) << 4);      // swizzled 16B col slot

  auto stageA = [&](int h, int i, int kt, int ldsbase) {
    const char* g = (const char*)A +
        (size_t)(bm * 256 + h * 128 + i * 64 + tr) * Kb + (size_t)kt * 128 + tc;
    gload_lds16(g, lds + ldsbase + h * 16384 + i * 8192 + w * 1024);
  };
  auto stageB = [&](int h, int i, int kt, int ldsbase) {
    const char* g = (const char*)Bm +
        (size_t)(bn * 256 + h * 128 + i * 64 + tr) * Kb + (size_t)kt * 128 + tc;
    gload_lds16(g, lds + ldsbase + 32768 + h * 16384 + i * 8192 + w * 1024);
  };

  // --- fragment read offsets ---
  // A row (within half) = wr*64 + fm*16 + (l&15); row&7 == l&7.
  // colbyte = kk*64 + (l>>4)*16, then ^ (l&7)<<4.
  const int arow = (wr * 64 + (l & 15)) * 128;
  const int brow = (wc * 32 + (l & 15)) * 128;
  const int ck0 = (((l >> 4) * 16)) ^ ((l & 7) << 4);
  const int ck1 = (64 + ((l >> 4) * 16)) ^ ((l & 7) << 4);

  f32x4 acc[8][4];
#pragma unroll
  for (int f = 0; f < 8; ++f)
#pragma unroll
    for (int g = 0; g < 4; ++g) acc[f][g] = (f32x4){0.f, 0.f, 0.f, 0.f};

  // --- prologue: kt0 full -> buf0 (8), kt1 A0,A1,B0 -> buf1 (6) ---
  stageA(0, 0, 0, 0); stageA(0, 1, 0, 0); stageA(1, 0, 0, 0); stageA(1, 1, 0, 0);
  stageB(0, 0, 0, 0); stageB(0, 1, 0, 0); stageB(1, 0, 0, 0); stageB(1, 1, 0, 0);
  stageA(0, 0, 1, 65536); stageA(0, 1, 1, 65536);
  stageA(1, 0, 1, 65536); stageA(1, 1, 1, 65536);
  stageB(0, 0, 1, 65536); stageB(0, 1, 1, 65536);
  VMCNT6();  // kt0's 8 loads retired; kt1's 6 in flight
  BAR();

  auto ktile = [&](int cur, int ktB1, int ktQ3, int vm) {
    bf16x8 a[4][2], b[2][2];
    const int ab = cur * 65536;
    const int ob = (cur ^ 1) * 65536;

    // ---- q0: quadrant (mh=0, nh=0): 8 A-reads + 4 B-reads ----
#pragma unroll
    for (int fm = 0; fm < 4; ++fm) {
      a[fm][0] = *(const bf16x8*)(lds + ab + 0 * 16384 + fm * 2048 + arow + ck0);
      a[fm][1] = *(const bf16x8*)(lds + ab + 0 * 16384 + fm * 2048 + arow + ck1);
    }
#pragma unroll
    for (int gn = 0; gn < 2; ++gn) {
      b[gn][0] = *(const bf16x8*)(lds + ab + 32768 + 0 * 16384 + gn * 2048 + brow + ck0);
      b[gn][1] = *(const bf16x8*)(lds + ab + 32768 + 0 * 16384 + gn * 2048 + brow + ck1);
    }
    if (ktB1 >= 0) { stageB(1, 0, ktB1, ob); stageB(1, 1, ktB1, ob); }
    BAR();
    __builtin_amdgcn_s_setprio(1);
#pragma unroll
    for (int fm = 0; fm < 4; ++fm)
#pragma unroll
      for (int gn = 0; gn < 2; ++gn)
#pragma unroll
        for (int kk = 0; kk < 2; ++kk)
          acc[fm][gn] = __builtin_amdgcn_mfma_f32_16x16x32_bf16(
              a[fm][kk], b[gn][kk], acc[fm][gn], 0, 0, 0);
    __builtin_amdgcn_s_setprio(0);
    BAR();

    // ---- q1: (mh=0, nh=1): reuse a, 4 B-reads ----
#pragma unroll
    for (int gn = 0; gn < 2; ++gn) {
      b[gn][0] = *(const bf16x8*)(lds + ab + 32768 + 1 * 16384 + gn * 2048 + brow + ck0);
      b[gn][1] = *(const bf16x8*)(lds + ab + 32768 + 1 * 16384 + gn * 2048 + brow + ck1);
    }
    BAR();
    __builtin_amdgcn_s_setprio(1);
#pragma unroll
    for (int fm = 0; fm < 4; ++fm)
#pragma unroll
      for (int gn = 0; gn < 2; ++gn)
#pragma unroll
        for (int kk = 0; kk < 2; ++kk)
          acc[fm][2 + gn] = __builtin_amdgcn_mfma_f32_16x16x32_bf16(
              a[fm][kk], b[gn][kk], acc[fm][2 + gn], 0, 0, 0);
    __builtin_amdgcn_s_setprio(0);
    BAR();

    // ---- q2: (mh=1, nh=0): 8 A-reads + 4 B-reads ----
#pragma unroll
    for (int fm = 0; fm < 4; ++fm) {
      a[fm][0] = *(const bf16x8*)(lds + ab + 1 * 16384 + fm * 2048 + arow + ck0);
      a[fm][1] = *(const bf16x8*)(lds + ab + 1 * 16384 + fm * 2048 + arow + ck1);
    }
#pragma unroll
    for (int gn = 0; gn < 2; ++gn) {
      b[gn][0] = *(const bf16x8*)(lds + ab + 32768 + 0 * 16384 + gn * 2048 + brow + ck0);
      b[gn][1] = *(const bf16x8*)(lds + ab + 32768 + 0 * 16384 + gn * 2048 + brow + ck1);
    }
    BAR();
    __builtin_amdgcn_s_setprio(1);
#pragma unroll
    for (int fm = 0; fm < 4; ++fm)
#pragma unroll
      for (int gn = 0; gn < 2; ++gn)
#pragma unroll
        for (int kk = 0; kk < 2; ++kk)
          acc[4 + fm][gn] = __builtin_amdgcn_mfma_f32_16x16x32_bf16(
              a[fm][kk], b[gn][kk], acc[4 + fm][gn], 0, 0, 0);
    __builtin_amdgcn_s_setprio(0);
    BAR();

    // ---- q3: (mh=1, nh=1): 4 B-reads; stage 6 of kt+2 -> current buf ----
#pragma unroll
    for (int gn = 0; gn < 2; ++gn) {
      b[gn][0] = *(const bf16x8*)(lds + ab + 32768 + 1 * 16384 + gn * 2048 + brow + ck0);
      b[gn][1] = *(const bf16x8*)(lds + ab + 32768 + 1 * 16384 + gn * 2048 + brow + ck1);
    }
    if (ktQ3 >= 0) {
      stageA(0, 0, ktQ3, ab); stageA(0, 1, ktQ3, ab);
      stageA(1, 0, ktQ3, ab); stageA(1, 1, ktQ3, ab);
      stageB(0, 0, ktQ3, ab); stageB(0, 1, ktQ3, ab);
    }
    if (vm == 6) VMCNT6();
    else if (vm == 0) VMCNT0();
    BAR();
    __builtin_amdgcn_s_setprio(1);
#pragma unroll
    for (int fm = 0; fm < 4; ++fm)
#pragma unroll
      for (int gn = 0; gn < 2; ++gn)
#pragma unroll
        for (int kk = 0; kk < 2; ++kk)
          acc[4 + fm][2 + gn] = __builtin_amdgcn_mfma_f32_16x16x32_bf16(
              a[fm][kk], b[gn][kk], acc[4 + fm][2 + gn], 0, 0, 0);
    __builtin_amdgcn_s_setprio(0);
    BAR();
  };

  for (int kt = 0; kt < NT - 2; ++kt) ktile(kt & 1, kt + 1, kt + 2, 6);
  ktile(0, NT - 1, -1, 0);   // kt = 62: stage B1(63); drain
  ktile(1, -1, -1, -1);      // kt = 63

  // ---- epilogue: C/D layout col=lane&15, row=(lane>>4)*4+reg ----
#pragma unroll
  for (int f = 0; f < 8; ++f) {
    const int row = bm * 256 + (f >> 2) * 128 + wr * 64 + (f & 3) * 16 + (l >> 4) * 4;
#pragma unroll
    for (int g = 0; g < 4; ++g) {
      const int col = bn * 256 + (g >> 1) * 128 + wc * 32 + (g & 1) * 16 + (l & 15);
#pragma unroll
      for (int r = 0; r < 4; ++r)
        C[(size_t)(row + r) * N + col] = acc[f][g][r];
    }
  }
}

// ---------------------------------------------------------------------------
extern "C" void kernel_launch(void* const* d_in, const int* in_sizes, int n_in,
                              void* d_out, int out_size, void* d_ws, size_t ws_size,
                              hipStream_t stream) {
  const float* x = (const float*)d_in[0];
  const int* qw = (const int*)d_in[1];
  const float* scale = (const float*)d_in[2];
  const float* zero = (const float*)d_in[3];
  float* out = (float*)d_out;

  const int K = 4096;
  const int N = 4096;
  const int M = in_sizes[0] / K;  // 8192

  unsigned short* xb = (unsigned short*)d_ws;   // M*K bf16
  unsigned short* wb = xb + (size_t)M * K;      // N*K bf16

  {
    int n4 = (M * K) / 4;
    xcast_kernel<<<(n4 + 255) / 256, 256, 0, stream>>>(x, xb, n4);
  }
  {
    int nthr = (N * (K / 2)) / 4;
    dequant_kernel<<<nthr / 256, 256, 0, stream>>>(qw, scale, zero, wb);
  }
  {
    dim3 grid((M / BM) * (N / BN));  // 32*16 = 512, %8 == 0
    gemm_bt_bf16<<<grid, 512, 0, stream>>>(xb, wb, out, M, N, K);
  }
}

// Round 9
// 481.954 us; speedup vs baseline: 1.2673x; 1.0048x over previous
//
#include <hip/hip_runtime.h>
#include <stdint.h>

// ---------------------------------------------------------------------------
// QuantizedLinear: out[M,N] = x[M,K] @ dequant(qweight)[N,K]^T
//   M = 8192, K = 4096, N = 4096; 4-bit weights, group=128, w = s*(q - z)
// (1) B fragments cached in registers across the K-tile
//   (ds_reads 32 -> 24 per K-tile: LDS throughput was the critical path,
//    256 reads x 12cyc = 3072 cyc > MFMA 2483 cyc). (2) xcast+dequant fused
//   into one dispatch to remove a launch gap.
// ---------------------------------------------------------------------------

typedef short bf16x8 __attribute__((ext_vector_type(8)));
typedef float f32x4 __attribute__((ext_vector_type(4)));
typedef unsigned short u16x8 __attribute__((ext_vector_type(8)));

#define BM 256
#define BN 256
#define BK 64
#define NT 64  // K / BK

#define BAR() asm volatile("s_barrier" ::: "memory")
#define VMCNT6() asm volatile("s_waitcnt vmcnt(6)" ::: "memory")
#define VMCNT0() asm volatile("s_waitcnt vmcnt(0)" ::: "memory")

// round-to-nearest-even f32 -> bf16 bits
__device__ __forceinline__ unsigned short f2bf(float f) {
  unsigned int u = __builtin_bit_cast(unsigned int, f);
  u += 0x7FFFu + ((u >> 16) & 1u);
  return (unsigned short)(u >> 16);
}

// async global->LDS, 16B/lane. LDS dest is wave-uniform base (+lane*16 by HW).
__device__ __forceinline__ void gload_lds16(const void* g, void* l) {
  const __attribute__((address_space(1))) unsigned int* gp =
      (const __attribute__((address_space(1))) unsigned int*)(uintptr_t)g;
  __attribute__((address_space(3))) unsigned int* lp =
      (__attribute__((address_space(3))) unsigned int*)(unsigned int)(uintptr_t)l;
  __builtin_amdgcn_global_load_lds(gp, lp, 16, 0, 0);
}

// ---------------------------------------------------------------------------
// Fused prep: blocks [0, XBLK): cast x fp32->bf16, 8 elems/thread.
//             blocks [XBLK, XBLK+QBLK): dequant 4 ints -> 8 bf16 /thread.
// ---------------------------------------------------------------------------
#define XBLK 16384  // (8192*4096/8)/256
#define QBLK 8192   // (4096*2048/4)/256

__global__ void prep_kernel(const float* __restrict__ x,
                            unsigned short* __restrict__ xb,
                            const int* __restrict__ qw,
                            const float* __restrict__ scale,
                            const float* __restrict__ zero,
                            unsigned short* __restrict__ wb) {
  const int bid = blockIdx.x;
  if (bid < XBLK) {
    int tid = bid * 256 + threadIdx.x;
    const float4* xp = reinterpret_cast<const float4*>(x) + (size_t)tid * 2;
    float4 v0 = xp[0];
    float4 v1 = xp[1];
    u16x8 o;
    o[0] = f2bf(v0.x); o[1] = f2bf(v0.y); o[2] = f2bf(v0.z); o[3] = f2bf(v0.w);
    o[4] = f2bf(v1.x); o[5] = f2bf(v1.y); o[6] = f2bf(v1.z); o[7] = f2bf(v1.w);
    reinterpret_cast<u16x8*>(xb)[tid] = o;
  } else {
    int tid = (bid - XBLK) * 256 + threadIdx.x;
    const int4 q = reinterpret_cast<const int4*>(qw)[tid];
    int pi0 = tid << 2;         // packed-int index
    int o = pi0 >> 11;          // 2048 ints per O-row
    int g = (pi0 & 2047) >> 6;  // 64 ints per group
    float s = scale[(o << 5) + g];
    float z = zero[(o << 5) + g];
    int qs[4] = {q.x, q.y, q.z, q.w};
    u16x8 ov;
#pragma unroll
    for (int j = 0; j < 4; ++j) {
      ov[2 * j]     = f2bf(((float)(qs[j] & 0xF) - z) * s);
      ov[2 * j + 1] = f2bf(((float)((qs[j] >> 4) & 0xF) - z) * s);
    }
    reinterpret_cast<u16x8*>(wb)[tid] = ov;
  }
}

// ---------------------------------------------------------------------------
// 256x256 8-phase GEMM-BT. LDS map (per buffer c at c*65536):
//   A: [half h][128 rows][64 cols bf16] at +h*16384 (row stride 128B)
//   B: same at +32768.
// Read swizzle: colbyte ^= (row&7)<<4. Linear LDS dest + inverse-swizzled
// global source (involution, rule #21).
// Per K-tile: q0 reads A0(8)+B0(4), stages B1(kt+1)->other buf;
//   q1 reads B1(4); q2 reads A1(8) (B cached in regs);
//   q3 reads nothing, stages A0,A1,B0(kt+2)->cur buf, vmcnt(6).
// ---------------------------------------------------------------------------
__global__ void __launch_bounds__(512, 2) gemm_bt_bf16(
    const unsigned short* __restrict__ A,  // [M][K] bf16 bits
    const unsigned short* __restrict__ Bm, // [N][K] bf16 bits
    float* __restrict__ C, int M, int N, int K) {
  __shared__ char lds[131072];

  const int t = threadIdx.x;
  const int w = t >> 6;   // wave 0..7
  const int l = t & 63;

  const int nbx = N / BN;      // 16
  const int nwg = gridDim.x;   // 512 (multiple of 8)
  const int bsw = (blockIdx.x & 7) * (nwg >> 3) + (blockIdx.x >> 3);
  const int bm = bsw / nbx;
  const int bn = bsw % nbx;

  const int wr = w >> 2;  // 0..1 (M)
  const int wc = w & 3;   // 0..3 (N)

  const size_t Kb = (size_t)K * 2;

  // --- staging per-thread source pieces (pre-swizzled global source) ---
  const int tr = w * 8 + (l >> 3);                 // row 0..63 within an issue
  const int tc = (((l & 7) ^ (l >> 3)) << 4);      // swizzled 16B col slot

  auto stageA = [&](int h, int i, int kt, int ldsbase) {
    const char* g = (const char*)A +
        (size_t)(bm * 256 + h * 128 + i * 64 + tr) * Kb + (size_t)kt * 128 + tc;
    gload_lds16(g, lds + ldsbase + h * 16384 + i * 8192 + w * 1024);
  };
  auto stageB = [&](int h, int i, int kt, int ldsbase) {
    const char* g = (const char*)Bm +
        (size_t)(bn * 256 + h * 128 + i * 64 + tr) * Kb + (size_t)kt * 128 + tc;
    gload_lds16(g, lds + ldsbase + 32768 + h * 16384 + i * 8192 + w * 1024);
  };

  // --- fragment read offsets ---
  const int arow = (wr * 64 + (l & 15)) * 128;
  const int brow = (wc * 32 + (l & 15)) * 128;
  const int ck0 = (((l >> 4) * 16)) ^ ((l & 7) << 4);
  const int ck1 = (64 + ((l >> 4) * 16)) ^ ((l & 7) << 4);

  f32x4 acc[8][4];
#pragma unroll
  for (int f = 0; f < 8; ++f)
#pragma unroll
    for (int g = 0; g < 4; ++g) acc[f][g] = (f32x4){0.f, 0.f, 0.f, 0.f};

  // --- prologue: kt0 full -> buf0 (8), kt1 A0,A1,B0 -> buf1 (6) ---
  stageA(0, 0, 0, 0); stageA(0, 1, 0, 0); stageA(1, 0, 0, 0); stageA(1, 1, 0, 0);
  stageB(0, 0, 0, 0); stageB(0, 1, 0, 0); stageB(1, 0, 0, 0); stageB(1, 1, 0, 0);
  stageA(0, 0, 1, 65536); stageA(0, 1, 1, 65536);
  stageA(1, 0, 1, 65536); stageA(1, 1, 1, 65536);
  stageB(0, 0, 1, 65536); stageB(0, 1, 1, 65536);
  VMCNT6();  // kt0's 8 loads retired; kt1's 6 in flight
  BAR();

  auto ktile = [&](int cur, int ktB1, int ktQ3, int vm) {
    bf16x8 a[4][2], b0[2][2], b1[2][2];
    const int ab = cur * 65536;
    const int ob = (cur ^ 1) * 65536;

    // ---- q0: read A-half0 (8) + B-half0 (4); stage B1(kt+1) -> other buf ----
#pragma unroll
    for (int fm = 0; fm < 4; ++fm) {
      a[fm][0] = *(const bf16x8*)(lds + ab + 0 * 16384 + fm * 2048 + arow + ck0);
      a[fm][1] = *(const bf16x8*)(lds + ab + 0 * 16384 + fm * 2048 + arow + ck1);
    }
#pragma unroll
    for (int gn = 0; gn < 2; ++gn) {
      b0[gn][0] = *(const bf16x8*)(lds + ab + 32768 + 0 * 16384 + gn * 2048 + brow + ck0);
      b0[gn][1] = *(const bf16x8*)(lds + ab + 32768 + 0 * 16384 + gn * 2048 + brow + ck1);
    }
    if (ktB1 >= 0) { stageB(1, 0, ktB1, ob); stageB(1, 1, ktB1, ob); }
    BAR();
    __builtin_amdgcn_s_setprio(1);
#pragma unroll
    for (int fm = 0; fm < 4; ++fm)
#pragma unroll
      for (int gn = 0; gn < 2; ++gn)
#pragma unroll
        for (int kk = 0; kk < 2; ++kk)
          acc[fm][gn] = __builtin_amdgcn_mfma_f32_16x16x32_bf16(
              a[fm][kk], b0[gn][kk], acc[fm][gn], 0, 0, 0);
    __builtin_amdgcn_s_setprio(0);
    BAR();

    // ---- q1: read B-half1 (4); MFMA (0,1) ----
#pragma unroll
    for (int gn = 0; gn < 2; ++gn) {
      b1[gn][0] = *(const bf16x8*)(lds + ab + 32768 + 1 * 16384 + gn * 2048 + brow + ck0);
      b1[gn][1] = *(const bf16x8*)(lds + ab + 32768 + 1 * 16384 + gn * 2048 + brow + ck1);
    }
    BAR();
    __builtin_amdgcn_s_setprio(1);
#pragma unroll
    for (int fm = 0; fm < 4; ++fm)
#pragma unroll
      for (int gn = 0; gn < 2; ++gn)
#pragma unroll
        for (int kk = 0; kk < 2; ++kk)
          acc[fm][2 + gn] = __builtin_amdgcn_mfma_f32_16x16x32_bf16(
              a[fm][kk], b1[gn][kk], acc[fm][2 + gn], 0, 0, 0);
    __builtin_amdgcn_s_setprio(0);
    BAR();

    // ---- q2: read A-half1 (8, overwrite a); MFMA (1,0) with cached b0 ----
#pragma unroll
    for (int fm = 0; fm < 4; ++fm) {
      a[fm][0] = *(const bf16x8*)(lds + ab + 1 * 16384 + fm * 2048 + arow + ck0);
      a[fm][1] = *(const bf16x8*)(lds + ab + 1 * 16384 + fm * 2048 + arow + ck1);
    }
    BAR();
    __builtin_amdgcn_s_setprio(1);
#pragma unroll
    for (int fm = 0; fm < 4; ++fm)
#pragma unroll
      for (int gn = 0; gn < 2; ++gn)
#pragma unroll
        for (int kk = 0; kk < 2; ++kk)
          acc[4 + fm][gn] = __builtin_amdgcn_mfma_f32_16x16x32_bf16(
              a[fm][kk], b0[gn][kk], acc[4 + fm][gn], 0, 0, 0);
    __builtin_amdgcn_s_setprio(0);
    BAR();

    // ---- q3: no reads; stage A0,A1,B0(kt+2) -> cur buf; MFMA (1,1) w/ b1 ----
    if (ktQ3 >= 0) {
      stageA(0, 0, ktQ3, ab); stageA(0, 1, ktQ3, ab);
      stageA(1, 0, ktQ3, ab); stageA(1, 1, ktQ3, ab);
      stageB(0, 0, ktQ3, ab); stageB(0, 1, ktQ3, ab);
    }
    if (vm == 6) VMCNT6();
    else if (vm == 0) VMCNT0();
    BAR();
    __builtin_amdgcn_s_setprio(1);
#pragma unroll
    for (int fm = 0; fm < 4; ++fm)
#pragma unroll
      for (int gn = 0; gn < 2; ++gn)
#pragma unroll
        for (int kk = 0; kk < 2; ++kk)
          acc[4 + fm][2 + gn] = __builtin_amdgcn_mfma_f32_16x16x32_bf16(
              a[fm][kk], b1[gn][kk], acc[4 + fm][2 + gn], 0, 0, 0);
    __builtin_amdgcn_s_setprio(0);
    BAR();
  };

  for (int kt = 0; kt < NT - 2; ++kt) ktile(kt & 1, kt + 1, kt + 2, 6);
  ktile(0, NT - 1, -1, 0);   // kt = 62: stage B1(63); drain
  ktile(1, -1, -1, -1);      // kt = 63

  // ---- epilogue: C/D layout col=lane&15, row=(lane>>4)*4+reg ----
#pragma unroll
  for (int f = 0; f < 8; ++f) {
    const int row = bm * 256 + (f >> 2) * 128 + wr * 64 + (f & 3) * 16 + (l >> 4) * 4;
#pragma unroll
    for (int g = 0; g < 4; ++g) {
      const int col = bn * 256 + (g >> 1) * 128 + wc * 32 + (g & 1) * 16 + (l & 15);
#pragma unroll
      for (int r = 0; r < 4; ++r)
        C[(size_t)(row + r) * N + col] = acc[f][g][r];
    }
  }
}

// ---------------------------------------------------------------------------
extern "C" void kernel_launch(void* const* d_in, const int* in_sizes, int n_in,
                              void* d_out, int out_size, void* d_ws, size_t ws_size,
                              hipStream_t stream) {
  const float* x = (const float*)d_in[0];
  const int* qw = (const int*)d_in[1];
  const float* scale = (const float*)d_in[2];
  const float* zero = (const float*)d_in[3];
  float* out = (float*)d_out;

  const int K = 4096;
  const int N = 4096;
  const int M = in_sizes[0] / K;  // 8192

  unsigned short* xb = (unsigned short*)d_ws;   // M*K bf16
  unsigned short* wb = xb + (size_t)M * K;      // N*K bf16

  prep_kernel<<<XBLK + QBLK, 256, 0, stream>>>(x, xb, qw, scale, zero, wb);

  dim3 grid((M / BM) * (N / BN));  // 32*16 = 512, %8 == 0
  gemm_bt_bf16<<<grid, 512, 0, stream>>>(xb, wb, out, M, N, K);
}

// Round 11
// 473.948 us; speedup vs baseline: 1.2887x; 1.0169x over previous
//
#include <hip/hip_runtime.h>
#include <stdint.h>

// ---------------------------------------------------------------------------
// QuantizedLinear: out[M,N] = x[M,K] @ dequant(qweight)[N,K]^T
//   M = 8192, K = 4096, N = 4096; 4-bit weights, group=128, w = s*(q - z)
// 2-barrier K-tile. Round 9 (8 barriers/K-tile) exposed the full LDS
// read-queue drain between barriers (~650 cyc/phase overhead, MfmaUtil
// stuck at 44%). Now: issue reads at tile top, compiler's fine-grained
// lgkmcnt(N) interleaves the drain under MFMA q0..q3; one lgkmcnt(0)+barrier
// before the in-place stage, one vmcnt(6)+barrier to certify the next buffer.
// ---------------------------------------------------------------------------

typedef short bf16x8 __attribute__((ext_vector_type(8)));
typedef float f32x4 __attribute__((ext_vector_type(4)));
typedef unsigned short u16x8 __attribute__((ext_vector_type(8)));

#define BM 256
#define BN 256
#define BK 64
#define NT 64  // K / BK

#define BAR() asm volatile("s_barrier" ::: "memory")
#define VMCNT6() asm volatile("s_waitcnt vmcnt(6)" ::: "memory")
#define VMCNT0() asm volatile("s_waitcnt vmcnt(0)" ::: "memory")
#define LGKM0() asm volatile("s_waitcnt lgkmcnt(0)" ::: "memory")

// round-to-nearest-even f32 -> bf16 bits
__device__ __forceinline__ unsigned short f2bf(float f) {
  unsigned int u = __builtin_bit_cast(unsigned int, f);
  u += 0x7FFFu + ((u >> 16) & 1u);
  return (unsigned short)(u >> 16);
}

// async global->LDS, 16B/lane. LDS dest is wave-uniform base (+lane*16 by HW).
__device__ __forceinline__ void gload_lds16(const void* g, void* l) {
  const __attribute__((address_space(1))) unsigned int* gp =
      (const __attribute__((address_space(1))) unsigned int*)(uintptr_t)g;
  __attribute__((address_space(3))) unsigned int* lp =
      (__attribute__((address_space(3))) unsigned int*)(unsigned int)(uintptr_t)l;
  __builtin_amdgcn_global_load_lds(gp, lp, 16, 0, 0);
}

// ---------------------------------------------------------------------------
// Fused prep: blocks [0, XBLK): cast x fp32->bf16, 8 elems/thread.
//             blocks [XBLK, XBLK+QBLK): dequant 4 ints -> 8 bf16 /thread.
// (Unchanged: non-GEMM time is constant ~214us across prep structures ->
//  fixed overhead, don't confound.)
// ---------------------------------------------------------------------------
#define XBLK 16384  // (8192*4096/8)/256
#define QBLK 8192   // (4096*2048/4)/256

__global__ void prep_kernel(const float* __restrict__ x,
                            unsigned short* __restrict__ xb,
                            const int* __restrict__ qw,
                            const float* __restrict__ scale,
                            const float* __restrict__ zero,
                            unsigned short* __restrict__ wb) {
  const int bid = blockIdx.x;
  if (bid < XBLK) {
    int tid = bid * 256 + threadIdx.x;
    const float4* xp = reinterpret_cast<const float4*>(x) + (size_t)tid * 2;
    float4 v0 = xp[0];
    float4 v1 = xp[1];
    u16x8 o;
    o[0] = f2bf(v0.x); o[1] = f2bf(v0.y); o[2] = f2bf(v0.z); o[3] = f2bf(v0.w);
    o[4] = f2bf(v1.x); o[5] = f2bf(v1.y); o[6] = f2bf(v1.z); o[7] = f2bf(v1.w);
    reinterpret_cast<u16x8*>(xb)[tid] = o;
  } else {
    int tid = (bid - XBLK) * 256 + threadIdx.x;
    const int4 q = reinterpret_cast<const int4*>(qw)[tid];
    int pi0 = tid << 2;         // packed-int index
    int o = pi0 >> 11;          // 2048 ints per O-row
    int g = (pi0 & 2047) >> 6;  // 64 ints per group
    float s = scale[(o << 5) + g];
    float z = zero[(o << 5) + g];
    int qs[4] = {q.x, q.y, q.z, q.w};
    u16x8 ov;
#pragma unroll
    for (int j = 0; j < 4; ++j) {
      ov[2 * j]     = f2bf(((float)(qs[j] & 0xF) - z) * s);
      ov[2 * j + 1] = f2bf(((float)((qs[j] >> 4) & 0xF) - z) * s);
    }
    reinterpret_cast<u16x8*>(wb)[tid] = ov;
  }
}

// ---------------------------------------------------------------------------
// 256x256 GEMM-BT, 2-barrier K-tile. LDS map (per buffer c at c*65536):
//   A: [half h][128 rows][64 cols bf16] at +h*16384 (row stride 128B)
//   B: same at +32768.
// Read swizzle: colbyte ^= (row&7)<<4. Linear LDS dest + inverse-swizzled
// global source (involution, rule #21).
// Per K-tile: read A0,B0,B1 (16) | stage B1(kt+1)->other | MFMA q0,q1
//   (compiler counted-lgkm under the drain) | read A1 (8, reuse regs) |
//   MFMA q2,q3 | lgkmcnt(0)+bar | stage A0,A1,B0(kt+2)->cur | vmcnt(6)+bar.
// ---------------------------------------------------------------------------
__global__ void __launch_bounds__(512, 2) gemm_bt_bf16(
    const unsigned short* __restrict__ A,  // [M][K] bf16 bits
    const unsigned short* __restrict__ Bm, // [N][K] bf16 bits
    float* __restrict__ C, int M, int N, int K) {
  __shared__ char lds[131072];

  const int t = threadIdx.x;
  const int w = t >> 6;   // wave 0..7
  const int l = t & 63;

  const int nbx = N / BN;      // 16
  const int nwg = gridDim.x;   // 512 (multiple of 8)
  const int bsw = (blockIdx.x & 7) * (nwg >> 3) + (blockIdx.x >> 3);
  const int bm = bsw / nbx;
  const int bn = bsw % nbx;

  const int wr = w >> 2;  // 0..1 (M)
  const int wc = w & 3;   // 0..3 (N)

  const size_t Kb = (size_t)K * 2;

  // --- staging per-thread source pieces (pre-swizzled global source) ---
  const int tr = w * 8 + (l >> 3);                 // row 0..63 within an issue
  const int tc = (((l & 7) ^ (l >> 3)) << 4);      // swizzled 16B col slot

  auto stageA = [&](int h, int i, int kt, int ldsbase) {
    const char* g = (const char*)A +
        (size_t)(bm * 256 + h * 128 + i * 64 + tr) * Kb + (size_t)kt * 128 + tc;
    gload_lds16(g, lds + ldsbase + h * 16384 + i * 8192 + w * 1024);
  };
  auto stageB = [&](int h, int i, int kt, int ldsbase) {
    const char* g = (const char*)Bm +
        (size_t)(bn * 256 + h * 128 + i * 64 + tr) * Kb + (size_t)kt * 128 + tc;
    gload_lds16(g, lds + ldsbase + 32768 + h * 16384 + i * 8192 + w * 1024);
  };

  // --- fragment read offsets ---
  const int arow = (wr * 64 + (l & 15)) * 128;
  const int brow = (wc * 32 + (l & 15)) * 128;
  const int ck0 = (((l >> 4) * 16)) ^ ((l & 7) << 4);
  const int ck1 = (64 + ((l >> 4) * 16)) ^ ((l & 7) << 4);

  f32x4 acc[8][4];
#pragma unroll
  for (int f = 0; f < 8; ++f)
#pragma unroll
    for (int g = 0; g < 4; ++g) acc[f][g] = (f32x4){0.f, 0.f, 0.f, 0.f};

  // --- prologue: kt0 full -> buf0 (8), kt1 A0,A1,B0 -> buf1 (6) ---
  stageA(0, 0, 0, 0); stageA(0, 1, 0, 0); stageA(1, 0, 0, 0); stageA(1, 1, 0, 0);
  stageB(0, 0, 0, 0); stageB(0, 1, 0, 0); stageB(1, 0, 0, 0); stageB(1, 1, 0, 0);
  stageA(0, 0, 1, 65536); stageA(0, 1, 1, 65536);
  stageA(1, 0, 1, 65536); stageA(1, 1, 1, 65536);
  stageB(0, 0, 1, 65536); stageB(0, 1, 1, 65536);
  VMCNT6();  // kt0's 8 loads retired; kt1's 6 in flight
  BAR();

  auto ktile = [&](int cur, int ktB1, int ktQ3, int vm) {
    bf16x8 a[4][2], b0[2][2], b1[2][2];
    const int ab = cur * 65536;
    const int ob = (cur ^ 1) * 65536;

    // ---- issue A-half0 (8) + B-half0 (4) + B-half1 (4) reads ----
#pragma unroll
    for (int fm = 0; fm < 4; ++fm) {
      a[fm][0] = *(const bf16x8*)(lds + ab + 0 * 16384 + fm * 2048 + arow + ck0);
      a[fm][1] = *(const bf16x8*)(lds + ab + 0 * 16384 + fm * 2048 + arow + ck1);
    }
#pragma unroll
    for (int gn = 0; gn < 2; ++gn) {
      b0[gn][0] = *(const bf16x8*)(lds + ab + 32768 + 0 * 16384 + gn * 2048 + brow + ck0);
      b0[gn][1] = *(const bf16x8*)(lds + ab + 32768 + 0 * 16384 + gn * 2048 + brow + ck1);
    }
#pragma unroll
    for (int gn = 0; gn < 2; ++gn) {
      b1[gn][0] = *(const bf16x8*)(lds + ab + 32768 + 1 * 16384 + gn * 2048 + brow + ck0);
      b1[gn][1] = *(const bf16x8*)(lds + ab + 32768 + 1 * 16384 + gn * 2048 + brow + ck1);
    }
    // ---- stage B1(kt+1) -> other buf (its readers finished at kt-1) ----
    if (ktB1 >= 0) { stageB(1, 0, ktB1, ob); stageB(1, 1, ktB1, ob); }

    // ---- q0: MFMA A0 x B0 (compiler counted-lgkm covers the drain) ----
    __builtin_amdgcn_s_setprio(1);
#pragma unroll
    for (int fm = 0; fm < 4; ++fm)
#pragma unroll
      for (int gn = 0; gn < 2; ++gn)
#pragma unroll
        for (int kk = 0; kk < 2; ++kk)
          acc[fm][gn] = __builtin_amdgcn_mfma_f32_16x16x32_bf16(
              a[fm][kk], b0[gn][kk], acc[fm][gn], 0, 0, 0);
    __builtin_amdgcn_s_setprio(0);

    // ---- q1: MFMA A0 x B1 ----
    __builtin_amdgcn_s_setprio(1);
#pragma unroll
    for (int fm = 0; fm < 4; ++fm)
#pragma unroll
      for (int gn = 0; gn < 2; ++gn)
#pragma unroll
        for (int kk = 0; kk < 2; ++kk)
          acc[fm][2 + gn] = __builtin_amdgcn_mfma_f32_16x16x32_bf16(
              a[fm][kk], b1[gn][kk], acc[fm][2 + gn], 0, 0, 0);
    __builtin_amdgcn_s_setprio(0);

    // ---- read A-half1 (8, reuse a[]; WAR-ordered after q1) ----
#pragma unroll
    for (int fm = 0; fm < 4; ++fm) {
      a[fm][0] = *(const bf16x8*)(lds + ab + 1 * 16384 + fm * 2048 + arow + ck0);
      a[fm][1] = *(const bf16x8*)(lds + ab + 1 * 16384 + fm * 2048 + arow + ck1);
    }

    // ---- q2: MFMA A1 x B0 ----
    __builtin_amdgcn_s_setprio(1);
#pragma unroll
    for (int fm = 0; fm < 4; ++fm)
#pragma unroll
      for (int gn = 0; gn < 2; ++gn)
#pragma unroll
        for (int kk = 0; kk < 2; ++kk)
          acc[4 + fm][gn] = __builtin_amdgcn_mfma_f32_16x16x32_bf16(
              a[fm][kk], b0[gn][kk], acc[4 + fm][gn], 0, 0, 0);
    __builtin_amdgcn_s_setprio(0);

    // ---- q3: MFMA A1 x B1 ----
    __builtin_amdgcn_s_setprio(1);
#pragma unroll
    for (int fm = 0; fm < 4; ++fm)
#pragma unroll
      for (int gn = 0; gn < 2; ++gn)
#pragma unroll
        for (int kk = 0; kk < 2; ++kk)
          acc[4 + fm][2 + gn] = __builtin_amdgcn_mfma_f32_16x16x32_bf16(
              a[fm][kk], b1[gn][kk], acc[4 + fm][2 + gn], 0, 0, 0);
    __builtin_amdgcn_s_setprio(0);

    // ---- certify all LDS reads complete (rule-18 fence), then overwrite ----
    LGKM0();
    __builtin_amdgcn_sched_barrier(0);
    BAR();
    if (ktQ3 >= 0) {
      stageA(0, 0, ktQ3, ab); stageA(0, 1, ktQ3, ab);
      stageA(1, 0, ktQ3, ab); stageA(1, 1, ktQ3, ab);
      stageB(0, 0, ktQ3, ab); stageB(0, 1, ktQ3, ab);
    }
    if (vm == 6) VMCNT6();
    else if (vm == 0) VMCNT0();
    BAR();
  };

  for (int kt = 0; kt < NT - 2; ++kt) ktile(kt & 1, kt + 1, kt + 2, 6);
  ktile(0, NT - 1, -1, 0);   // kt = 62: stage B1(63); drain
  ktile(1, -1, -1, -1);      // kt = 63

  // ---- epilogue: C/D layout col=lane&15, row=(lane>>4)*4+reg ----
#pragma unroll
  for (int f = 0; f < 8; ++f) {
    const int row = bm * 256 + (f >> 2) * 128 + wr * 64 + (f & 3) * 16 + (l >> 4) * 4;
#pragma unroll
    for (int g = 0; g < 4; ++g) {
      const int col = bn * 256 + (g >> 1) * 128 + wc * 32 + (g & 1) * 16 + (l & 15);
#pragma unroll
      for (int r = 0; r < 4; ++r)
        C[(size_t)(row + r) * N + col] = acc[f][g][r];
    }
  }
}

// ---------------------------------------------------------------------------
extern "C" void kernel_launch(void* const* d_in, const int* in_sizes, int n_in,
                              void* d_out, int out_size, void* d_ws, size_t ws_size,
                              hipStream_t stream) {
  const float* x = (const float*)d_in[0];
  const int* qw = (const int*)d_in[1];
  const float* scale = (const float*)d_in[2];
  const float* zero = (const float*)d_in[3];
  float* out = (float*)d_out;

  const int K = 4096;
  const int N = 4096;
  const int M = in_sizes[0] / K;  // 8192

  unsigned short* xb = (unsigned short*)d_ws;   // M*K bf16
  unsigned short* wb = xb + (size_t)M * K;      // N*K bf16

  prep_kernel<<<XBLK + QBLK, 256, 0, stream>>>(x, xb, qw, scale, zero, wb);

  dim3 grid((M / BM) * (N / BN));  // 32*16 = 512, %8 == 0
  gemm_bt_bf16<<<grid, 512, 0, stream>>>(xb, wb, out, M, N, K);
}